// Round 4
// baseline (215.843 us; speedup 1.0000x reference)
//
#include <hip/hip_runtime.h>

#define IMG   512
#define NIMG  32
#define TX    64
#define TY    16
#define VQ    20          /* sV row stride in quads; 20%8==4 -> phase-balanced banks */
#define NPIX  (32.0f * 512.0f * 512.0f)

constexpr float GW[11] = {
    0.00102838f, 0.00759876f, 0.03600077f, 0.10936069f, 0.21300553f,
    0.26601174f,
    0.21300553f, 0.10936069f, 0.03600077f, 0.00759876f, 0.00102838f
};
constexpr float C1c = 0.0001f;
constexpr float C2c = 0.0009f;

__global__ void ssim_init_out(float* __restrict__ out) { out[0] = 1.0f; }

__device__ __forceinline__ float4 f4mul(float4 a, float4 b) {
    return make_float4(a.x * b.x, a.y * b.y, a.z * b.z, a.w * b.w);
}
__device__ __forceinline__ float4 f4fma(float w, float4 v, float4 c) {
    return make_float4(fmaf(w, v.x, c.x), fmaf(w, v.y, c.y),
                       fmaf(w, v.z, c.z), fmaf(w, v.w, c.w));
}

__global__ __launch_bounds__(256, 5) void ssim_fused(
        const float* __restrict__ img1, const float* __restrict__ img2,
        float* __restrict__ out) {
    // Only the v-conv intermediate lives in LDS: 5ch x 16rows x 20quads x 16B
    // = 25.6 KB -> 5+ blocks/CU. Input is read straight from global (L1/L2
    // absorb the halo re-reads).
    __shared__ float4 sV4[5 * TY * VQ];

    const int tid = threadIdx.x;
    const int X0 = blockIdx.x * TX;
    const int Y0 = blockIdx.y * TY;
    const int n  = blockIdx.z;
    const float* a0 = img1 + (size_t)n * IMG * IMG;
    const float* b0 = img2 + (size_t)n * IMG * IMG;

    // ---- vertical pass straight from global: 5 channels, 2 out rows/thread
    // items: q in [0,20) x row-pair g in [0,8) -> 160 threads
    if (tid < 160) {
        const int q  = tid % 20;
        const int g  = tid / 20;
        const int y0 = 2 * g;                  // first local output row
        const int gx0 = X0 - 8 + 4 * q;        // 16B-aligned global col
        const bool okx = (gx0 >= 0) && (gx0 < IMG);
        const int gyb = Y0 + y0 - 5;

        float4 acc[5][2];
#pragma unroll
        for (int ch = 0; ch < 5; ++ch)
#pragma unroll
            for (int o = 0; o < 2; ++o)
                acc[ch][o] = make_float4(0.f, 0.f, 0.f, 0.f);

#pragma unroll
        for (int k = 0; k < 12; ++k) {
            const int gy = gyb + k;
            const bool ok = okx && ((unsigned)gy < IMG);
            float4 a = make_float4(0.f, 0.f, 0.f, 0.f);
            float4 b = make_float4(0.f, 0.f, 0.f, 0.f);
            if (ok) {
                const int off = gy * IMG + gx0;
                a = *(const float4*)(a0 + off);
                b = *(const float4*)(b0 + off);
            }
            const float4 aa = f4mul(a, a);
            const float4 bb = f4mul(b, b);
            const float4 ab = f4mul(a, b);
            if (k <= 10) {
                const float w = GW[k];
                acc[0][0] = f4fma(w, a,  acc[0][0]);
                acc[1][0] = f4fma(w, b,  acc[1][0]);
                acc[2][0] = f4fma(w, aa, acc[2][0]);
                acc[3][0] = f4fma(w, bb, acc[3][0]);
                acc[4][0] = f4fma(w, ab, acc[4][0]);
            }
            if (k >= 1) {
                const float w = GW[k - 1];
                acc[0][1] = f4fma(w, a,  acc[0][1]);
                acc[1][1] = f4fma(w, b,  acc[1][1]);
                acc[2][1] = f4fma(w, aa, acc[2][1]);
                acc[3][1] = f4fma(w, bb, acc[3][1]);
                acc[4][1] = f4fma(w, ab, acc[4][1]);
            }
        }
#pragma unroll
        for (int o = 0; o < 2; ++o)
#pragma unroll
            for (int ch = 0; ch < 5; ++ch)
                sV4[ch * (TY * VQ) + (y0 + o) * VQ + q] = acc[ch][o];
    }
    __syncthreads();

    // ---- horizontal pass + ssim: one (row, out-quad) per thread, 256 items
    float sum = 0.0f;
    {
        const int y = tid >> 4;        // 0..15
        const int c = tid & 15;        // output quad: cols 4c..4c+3
        float4 res[5];
#pragma unroll
        for (int ch = 0; ch < 5; ++ch) {
            const float4* row = &sV4[ch * (TY * VQ) + y * VQ];
            float v[20];
#pragma unroll
            for (int d = 0; d < 5; ++d) {
                const float4 t = row[c + d];
                v[4 * d + 0] = t.x; v[4 * d + 1] = t.y;
                v[4 * d + 2] = t.z; v[4 * d + 3] = t.w;
            }
            float r[4];
#pragma unroll
            for (int e = 0; e < 4; ++e) {
                float s = GW[0] * v[e + 3];
#pragma unroll
                for (int k = 1; k < 11; ++k) s = fmaf(GW[k], v[e + 3 + k], s);
                r[e] = s;
            }
            res[ch] = make_float4(r[0], r[1], r[2], r[3]);
        }
        const float* mu1 = (const float*)&res[0];
        const float* mu2 = (const float*)&res[1];
        const float* x11 = (const float*)&res[2];
        const float* x22 = (const float*)&res[3];
        const float* x12 = (const float*)&res[4];
#pragma unroll
        for (int e = 0; e < 4; ++e) {
            const float m1s = mu1[e] * mu1[e];
            const float m2s = mu2[e] * mu2[e];
            const float m12 = mu1[e] * mu2[e];
            const float s1  = x11[e] - m1s;
            const float s2  = x22[e] - m2s;
            const float s12 = x12[e] - m12;
            const float num = (2.0f * m12 + C1c) * (2.0f * s12 + C2c);
            const float den = (m1s + m2s + C1c) * (s1 + s2 + C2c);
            sum += num / den;
        }
    }

    // ---- block reduction ----
#pragma unroll
    for (int off = 32; off > 0; off >>= 1)
        sum += __shfl_down(sum, off, 64);

    __shared__ float wred[4];
    if ((tid & 63) == 0) wred[tid >> 6] = sum;
    __syncthreads();
    if (tid == 0) {
        const float s = wred[0] + wred[1] + wred[2] + wred[3];
        atomicAdd(out, -s * (1.0f / NPIX));
    }
}

extern "C" void kernel_launch(void* const* d_in, const int* in_sizes, int n_in,
                              void* d_out, int out_size, void* d_ws, size_t ws_size,
                              hipStream_t stream) {
    const float* img1 = (const float*)d_in[0];
    const float* img2 = (const float*)d_in[1];
    float* out = (float*)d_out;

    ssim_init_out<<<1, 1, 0, stream>>>(out);

    dim3 grid(IMG / TX, IMG / TY, NIMG);   // 8 x 32 x 32 = 8192 blocks
    ssim_fused<<<grid, 256, 0, stream>>>(img1, img2, out);
}

// Round 5
// 194.740 us; speedup vs baseline: 1.1084x; 1.1084x over previous
//
#include <hip/hip_runtime.h>

#define IMG   512
#define NIMG  32
#define TX    64
#define TY    16
#define VQS   17                  /* sV per-quad (column-strip) stride, in quads */
#define VPL   (20 * VQS)          /* quads per channel plane = 340 */
#define NPIX  (32.0f * 512.0f * 512.0f)

constexpr float GW[11] = {
    0.00102838f, 0.00759876f, 0.03600077f, 0.10936069f, 0.21300553f,
    0.26601174f,
    0.21300553f, 0.10936069f, 0.03600077f, 0.00759876f, 0.00102838f
};
constexpr float C1c = 0.0001f;
constexpr float C2c = 0.0009f;

__global__ void ssim_init_out(float* __restrict__ out) { out[0] = 1.0f; }

__device__ __forceinline__ float4 f4mul(float4 a, float4 b) {
    return make_float4(a.x * b.x, a.y * b.y, a.z * b.z, a.w * b.w);
}
__device__ __forceinline__ float4 f4fma(float w, float4 v, float4 c) {
    return make_float4(fmaf(w, v.x, c.x), fmaf(w, v.y, c.y),
                       fmaf(w, v.z, c.z), fmaf(w, v.w, c.w));
}

__global__ __launch_bounds__(256) void ssim_fused(
        const float* __restrict__ img1, const float* __restrict__ img2,
        float* __restrict__ out) {
    // sV transposed: [ch][quad q][row y], stride 17 quads per q.
    // 5 * 340 quads * 16B = 27.2 KB -> 5 blocks/CU.
    __shared__ float4 sV4[5 * VPL];

    const int tid = threadIdx.x;
    const int X0 = blockIdx.x * TX;
    const int Y0 = blockIdx.y * TY;
    const int n  = blockIdx.z;
    const float* a0 = img1 + (size_t)n * IMG * IMG;
    const float* b0 = img2 + (size_t)n * IMG * IMG;

    // ---- vertical pass straight from global: 5 channels, 2 out rows/thread
    // items: q in [0,20) x row-pair g in [0,8) -> 160 threads
    if (tid < 160) {
        const int q  = tid % 20;
        const int g  = tid / 20;
        const int y0 = 2 * g;                  // first local output row
        const int gx0 = X0 - 8 + 4 * q;        // 16B-aligned global col
        const bool okx = (gx0 >= 0) && (gx0 < IMG);
        const int gyb = Y0 + y0 - 5;

        float4 acc[5][2];
#pragma unroll
        for (int ch = 0; ch < 5; ++ch)
#pragma unroll
            for (int o = 0; o < 2; ++o)
                acc[ch][o] = make_float4(0.f, 0.f, 0.f, 0.f);

#pragma unroll
        for (int k = 0; k < 12; ++k) {
            const int gy = gyb + k;
            const bool ok = okx && ((unsigned)gy < IMG);
            float4 a = make_float4(0.f, 0.f, 0.f, 0.f);
            float4 b = make_float4(0.f, 0.f, 0.f, 0.f);
            if (ok) {
                const int off = gy * IMG + gx0;
                a = *(const float4*)(a0 + off);
                b = *(const float4*)(b0 + off);
            }
            const float4 aa = f4mul(a, a);
            const float4 bb = f4mul(b, b);
            const float4 ab = f4mul(a, b);
            if (k <= 10) {
                const float w = GW[k];
                acc[0][0] = f4fma(w, a,  acc[0][0]);
                acc[1][0] = f4fma(w, b,  acc[1][0]);
                acc[2][0] = f4fma(w, aa, acc[2][0]);
                acc[3][0] = f4fma(w, bb, acc[3][0]);
                acc[4][0] = f4fma(w, ab, acc[4][0]);
            }
            if (k >= 1) {
                const float w = GW[k - 1];
                acc[0][1] = f4fma(w, a,  acc[0][1]);
                acc[1][1] = f4fma(w, b,  acc[1][1]);
                acc[2][1] = f4fma(w, aa, acc[2][1]);
                acc[3][1] = f4fma(w, bb, acc[3][1]);
                acc[4][1] = f4fma(w, ab, acc[4][1]);
            }
        }
#pragma unroll
        for (int o = 0; o < 2; ++o)
#pragma unroll
            for (int ch = 0; ch < 5; ++ch)
                sV4[ch * VPL + q * VQS + (y0 + o)] = acc[ch][o];
    }
    __syncthreads();

    // ---- horizontal pass + ssim. Lane map: y fast (tid&15), c = tid>>4,
    // so each 16-lane group reads 16 consecutive float4s: bank-perfect.
    float sum = 0.0f;
    {
        const int y = tid & 15;        // row 0..15
        const int c = tid >> 4;        // output quad: cols 4c..4c+3
        float4 res[5];
#pragma unroll
        for (int ch = 0; ch < 5; ++ch) {
            const float4* base = &sV4[ch * VPL + y];
            float v[20];
#pragma unroll
            for (int d = 0; d < 5; ++d) {
                const float4 t = base[(c + d) * VQS];
                v[4 * d + 0] = t.x; v[4 * d + 1] = t.y;
                v[4 * d + 2] = t.z; v[4 * d + 3] = t.w;
            }
            float r[4];
#pragma unroll
            for (int e = 0; e < 4; ++e) {
                float s = GW[0] * v[e + 3];
#pragma unroll
                for (int k = 1; k < 11; ++k) s = fmaf(GW[k], v[e + 3 + k], s);
                r[e] = s;
            }
            res[ch] = make_float4(r[0], r[1], r[2], r[3]);
        }
        const float* mu1 = (const float*)&res[0];
        const float* mu2 = (const float*)&res[1];
        const float* x11 = (const float*)&res[2];
        const float* x22 = (const float*)&res[3];
        const float* x12 = (const float*)&res[4];
#pragma unroll
        for (int e = 0; e < 4; ++e) {
            const float m1s = mu1[e] * mu1[e];
            const float m2s = mu2[e] * mu2[e];
            const float m12 = mu1[e] * mu2[e];
            const float s1  = x11[e] - m1s;
            const float s2  = x22[e] - m2s;
            const float s12 = x12[e] - m12;
            const float num = (2.0f * m12 + C1c) * (2.0f * s12 + C2c);
            const float den = (m1s + m2s + C1c) * (s1 + s2 + C2c);
            sum += num / den;
        }
    }

    // ---- block reduction ----
#pragma unroll
    for (int off = 32; off > 0; off >>= 1)
        sum += __shfl_down(sum, off, 64);

    __shared__ float wred[4];
    if ((tid & 63) == 0) wred[tid >> 6] = sum;
    __syncthreads();
    if (tid == 0) {
        const float s = wred[0] + wred[1] + wred[2] + wred[3];
        atomicAdd(out, -s * (1.0f / NPIX));
    }
}

extern "C" void kernel_launch(void* const* d_in, const int* in_sizes, int n_in,
                              void* d_out, int out_size, void* d_ws, size_t ws_size,
                              hipStream_t stream) {
    const float* img1 = (const float*)d_in[0];
    const float* img2 = (const float*)d_in[1];
    float* out = (float*)d_out;

    ssim_init_out<<<1, 1, 0, stream>>>(out);

    dim3 grid(IMG / TX, IMG / TY, NIMG);   // 8 x 32 x 32 = 8192 blocks
    ssim_fused<<<grid, 256, 0, stream>>>(img1, img2, out);
}

// Round 6
// 146.603 us; speedup vs baseline: 1.4723x; 1.3284x over previous
//
#include <hip/hip_runtime.h>

#define IMG   512
#define NIMG  32
#define TX    64
#define TY    16
#define VQS   17                  /* sV per-quad (column-strip) stride, in quads */
#define VPL   (20 * VQS)          /* quads per channel plane = 340 */
#define NBLK  (8 * 32 * 32)       /* 8192 tile blocks */
#define NPIX  (32.0f * 512.0f * 512.0f)

constexpr float GW[11] = {
    0.00102838f, 0.00759876f, 0.03600077f, 0.10936069f, 0.21300553f,
    0.26601174f,
    0.21300553f, 0.10936069f, 0.03600077f, 0.00759876f, 0.00102838f
};
constexpr float C1c = 0.0001f;
constexpr float C2c = 0.0009f;

__global__ void ssim_init_out(float* __restrict__ out) { out[0] = 1.0f; }

__device__ __forceinline__ float4 f4mul(float4 a, float4 b) {
    return make_float4(a.x * b.x, a.y * b.y, a.z * b.z, a.w * b.w);
}
__device__ __forceinline__ float4 f4fma(float w, float4 v, float4 c) {
    return make_float4(fmaf(w, v.x, c.x), fmaf(w, v.y, c.y),
                       fmaf(w, v.z, c.z), fmaf(w, v.w, c.w));
}

__global__ __launch_bounds__(256, 3) void ssim_fused(
        const float* __restrict__ img1, const float* __restrict__ img2,
        float* __restrict__ ws, float* __restrict__ out) {
    // sV transposed: [ch][quad q][row y], stride 17 quads per q strip.
    // 5 * 340 * 16B = 27.2 KB -> 5 blocks/CU (LDS-limited).
    __shared__ float4 sV4[5 * VPL];

    const int tid = threadIdx.x;
    const int X0 = blockIdx.x * TX;
    const int Y0 = blockIdx.y * TY;
    const int n  = blockIdx.z;
    const float* a0 = img1 + (size_t)n * IMG * IMG;
    const float* b0 = img2 + (size_t)n * IMG * IMG;

    // ---- vertical pass straight from global: 5 channels, 2 out rows/thread
    // item map: q = tid>>3 (0..19), g = tid&7 -> sV writes are 2-way/phase
    if (tid < 160) {
        const int q  = tid >> 3;
        const int g  = tid & 7;
        const int y0 = 2 * g;                  // first local output row
        const int gx0 = X0 - 8 + 4 * q;        // 16B-aligned global col
        const bool okx = (gx0 >= 0) && (gx0 < IMG);
        const int gyb = Y0 + y0 - 5;

        float4 acc[5][2];
#pragma unroll
        for (int ch = 0; ch < 5; ++ch)
#pragma unroll
            for (int o = 0; o < 2; ++o)
                acc[ch][o] = make_float4(0.f, 0.f, 0.f, 0.f);

        float4 ra[6], rb[6];
#pragma unroll
        for (int half = 0; half < 2; ++half) {
            // batch-issue 12 loads (6 rows x 2 images)
#pragma unroll
            for (int j = 0; j < 6; ++j) {
                const int gy = gyb + half * 6 + j;
                const bool ok = okx && ((unsigned)gy < IMG);
                ra[j] = make_float4(0.f, 0.f, 0.f, 0.f);
                rb[j] = make_float4(0.f, 0.f, 0.f, 0.f);
                if (ok) {
                    const int off = gy * IMG + gx0;
                    ra[j] = *(const float4*)(a0 + off);
                    rb[j] = *(const float4*)(b0 + off);
                }
            }
            // accumulate the 6 rows
#pragma unroll
            for (int j = 0; j < 6; ++j) {
                const int k = half * 6 + j;
                const float4 a = ra[j];
                const float4 b = rb[j];
                const float4 aa = f4mul(a, a);
                const float4 bb = f4mul(b, b);
                const float4 ab = f4mul(a, b);
                if (k <= 10) {
                    const float w = GW[k];
                    acc[0][0] = f4fma(w, a,  acc[0][0]);
                    acc[1][0] = f4fma(w, b,  acc[1][0]);
                    acc[2][0] = f4fma(w, aa, acc[2][0]);
                    acc[3][0] = f4fma(w, bb, acc[3][0]);
                    acc[4][0] = f4fma(w, ab, acc[4][0]);
                }
                if (k >= 1) {
                    const float w = GW[k - 1];
                    acc[0][1] = f4fma(w, a,  acc[0][1]);
                    acc[1][1] = f4fma(w, b,  acc[1][1]);
                    acc[2][1] = f4fma(w, aa, acc[2][1]);
                    acc[3][1] = f4fma(w, bb, acc[3][1]);
                    acc[4][1] = f4fma(w, ab, acc[4][1]);
                }
            }
        }
#pragma unroll
        for (int o = 0; o < 2; ++o)
#pragma unroll
            for (int ch = 0; ch < 5; ++ch)
                sV4[ch * VPL + q * VQS + (y0 + o)] = acc[ch][o];
    }
    __syncthreads();

    // ---- horizontal pass + ssim. y fast (tid&15), c = tid>>4: each 16-lane
    // phase reads 16 consecutive float4s -> 2-way (free).
    float sum = 0.0f;
    {
        const int y = tid & 15;        // row 0..15
        const int c = tid >> 4;        // output quad: cols 4c..4c+3
        float4 res[5];
#pragma unroll
        for (int ch = 0; ch < 5; ++ch) {
            const float4* base = &sV4[ch * VPL + y];
            float v[20];
#pragma unroll
            for (int d = 0; d < 5; ++d) {
                const float4 t = base[(c + d) * VQS];
                v[4 * d + 0] = t.x; v[4 * d + 1] = t.y;
                v[4 * d + 2] = t.z; v[4 * d + 3] = t.w;
            }
            float r[4];
#pragma unroll
            for (int e = 0; e < 4; ++e) {
                float s = GW[0] * v[e + 3];
#pragma unroll
                for (int k = 1; k < 11; ++k) s = fmaf(GW[k], v[e + 3 + k], s);
                r[e] = s;
            }
            res[ch] = make_float4(r[0], r[1], r[2], r[3]);
        }
        const float* mu1 = (const float*)&res[0];
        const float* mu2 = (const float*)&res[1];
        const float* x11 = (const float*)&res[2];
        const float* x22 = (const float*)&res[3];
        const float* x12 = (const float*)&res[4];
#pragma unroll
        for (int e = 0; e < 4; ++e) {
            const float m1s = mu1[e] * mu1[e];
            const float m2s = mu2[e] * mu2[e];
            const float m12 = mu1[e] * mu2[e];
            const float s1  = x11[e] - m1s;
            const float s2  = x22[e] - m2s;
            const float s12 = x12[e] - m12;
            const float num = (2.0f * m12 + C1c) * (2.0f * s12 + C2c);
            const float den = (m1s + m2s + C1c) * (s1 + s2 + C2c);
            sum += num / den;
        }
    }

    // ---- block reduction ----
#pragma unroll
    for (int off = 32; off > 0; off >>= 1)
        sum += __shfl_down(sum, off, 64);

    __shared__ float wred[4];
    if ((tid & 63) == 0) wred[tid >> 6] = sum;
    __syncthreads();
    if (tid == 0) {
        const float s = wred[0] + wred[1] + wred[2] + wred[3];
        if (ws) {
            const int bid = blockIdx.x +
                (int)gridDim.x * (blockIdx.y + (int)gridDim.y * blockIdx.z);
            ws[bid] = s;
        } else {
            atomicAdd(out, -s * (1.0f / NPIX));
        }
    }
}

__global__ __launch_bounds__(1024) void ssim_reduce(
        const float* __restrict__ ws, float* __restrict__ out) {
    const int t = threadIdx.x;
    float s = 0.0f;
    for (int i = t; i < NBLK; i += 1024) s += ws[i];
#pragma unroll
    for (int off = 32; off > 0; off >>= 1)
        s += __shfl_down(s, off, 64);
    __shared__ float wr[16];
    if ((t & 63) == 0) wr[t >> 6] = s;
    __syncthreads();
    if (t < 64) {
        float v = (t < 16) ? wr[t] : 0.0f;
#pragma unroll
        for (int off = 8; off > 0; off >>= 1)
            v += __shfl_down(v, off, 64);
        if (t == 0) out[0] = 1.0f - v * (1.0f / NPIX);
    }
}

extern "C" void kernel_launch(void* const* d_in, const int* in_sizes, int n_in,
                              void* d_out, int out_size, void* d_ws, size_t ws_size,
                              hipStream_t stream) {
    const float* img1 = (const float*)d_in[0];
    const float* img2 = (const float*)d_in[1];
    float* out = (float*)d_out;
    const bool two_stage = (d_ws != nullptr) && (ws_size >= NBLK * sizeof(float));
    float* ws = two_stage ? (float*)d_ws : nullptr;

    if (!two_stage) ssim_init_out<<<1, 1, 0, stream>>>(out);

    dim3 grid(IMG / TX, IMG / TY, NIMG);   // 8 x 32 x 32 = 8192 blocks
    ssim_fused<<<grid, 256, 0, stream>>>(img1, img2, ws, out);

    if (two_stage) ssim_reduce<<<1, 1024, 0, stream>>>(ws, out);
}

// Round 7
// 120.416 us; speedup vs baseline: 1.7925x; 1.2175x over previous
//
#include <hip/hip_runtime.h>

#define IMG   512
#define NIMG  32
#define TX    128
#define TY    16
#define NQ    36                  /* staged quad strips per block */
#define VQS   17                  /* sV strip stride in quads (16 rows + 1 pad) */
#define VPL   (NQ * VQS)          /* 612 quads per channel plane */
#define VITEMS (NQ * 8)           /* 288 v-pass items */
#define NBX   (IMG / TX)          /* 4 */
#define NBY   (IMG / TY)          /* 32 */
#define NBLK  (NBX * NBY * NIMG)  /* 4096 */
#define NPIX  (32.0f * 512.0f * 512.0f)

constexpr float GW[11] = {
    0.00102838f, 0.00759876f, 0.03600077f, 0.10936069f, 0.21300553f,
    0.26601174f,
    0.21300553f, 0.10936069f, 0.03600077f, 0.00759876f, 0.00102838f
};
constexpr float C1c = 0.0001f;
constexpr float C2c = 0.0009f;

__global__ void ssim_init_out(float* __restrict__ out) { out[0] = 1.0f; }

__device__ __forceinline__ float4 f4mul(float4 a, float4 b) {
    return make_float4(a.x * b.x, a.y * b.y, a.z * b.z, a.w * b.w);
}
__device__ __forceinline__ float4 f4fma(float w, float4 v, float4 c) {
    return make_float4(fmaf(w, v.x, c.x), fmaf(w, v.y, c.y),
                       fmaf(w, v.z, c.z), fmaf(w, v.w, c.w));
}

// One v-pass item: strip q, row-pair g. Computes 5 vertical convs for 2
// output rows of one float4 column strip, writes to transposed sV.
// INTERIOR: no bounds code at all. Boundary: clamped addresses (always
// valid) + weight-kill (exact zero-pad semantics).
template <bool INTERIOR>
__device__ __forceinline__ void vpass_item(int it, int X0, int Y0,
        const float* __restrict__ a0, const float* __restrict__ b0,
        float4* __restrict__ sV4) {
    const int q  = it % NQ;
    const int g  = it / NQ;
    const int y0 = 2 * g;
    int gx0 = X0 - 8 + 4 * q;
    const int gyb = Y0 + y0 - 5;
    bool okx = true;
    if (!INTERIOR) {
        okx = (gx0 >= 0) && (gx0 + 3 < IMG);
        gx0 = min(max(gx0, 0), IMG - 4);
    }

    float4 acc[5][2];
#pragma unroll
    for (int ch = 0; ch < 5; ++ch)
#pragma unroll
        for (int o = 0; o < 2; ++o)
            acc[ch][o] = make_float4(0.f, 0.f, 0.f, 0.f);

    float4 ra[6], rb[6];
#pragma unroll
    for (int half = 0; half < 2; ++half) {
        // batch-issue 12 loads (6 rows x 2 images), addresses always valid
#pragma unroll
        for (int j = 0; j < 6; ++j) {
            int gy = gyb + half * 6 + j;
            if (!INTERIOR) gy = min(max(gy, 0), IMG - 1);
            const int off = gy * IMG + gx0;
            ra[j] = *(const float4*)(a0 + off);
            rb[j] = *(const float4*)(b0 + off);
        }
#pragma unroll
        for (int j = 0; j < 6; ++j) {
            const int k = half * 6 + j;
            const float4 a = ra[j];
            const float4 b = rb[j];
            const float4 aa = f4mul(a, a);
            const float4 bb = f4mul(b, b);
            const float4 ab = f4mul(a, b);
            if (INTERIOR) {
                if (k <= 10) {
                    const float w = GW[k];
                    acc[0][0] = f4fma(w, a,  acc[0][0]);
                    acc[1][0] = f4fma(w, b,  acc[1][0]);
                    acc[2][0] = f4fma(w, aa, acc[2][0]);
                    acc[3][0] = f4fma(w, bb, acc[3][0]);
                    acc[4][0] = f4fma(w, ab, acc[4][0]);
                }
                if (k >= 1) {
                    const float w = GW[k - 1];
                    acc[0][1] = f4fma(w, a,  acc[0][1]);
                    acc[1][1] = f4fma(w, b,  acc[1][1]);
                    acc[2][1] = f4fma(w, aa, acc[2][1]);
                    acc[3][1] = f4fma(w, bb, acc[3][1]);
                    acc[4][1] = f4fma(w, ab, acc[4][1]);
                }
            } else {
                const int gy = gyb + k;
                const bool ok = okx && ((unsigned)gy < IMG);
                float w0 = (k <= 10) ? GW[k] : 0.0f;
                float w1 = (k >= 1) ? GW[k - 1] : 0.0f;
                w0 = ok ? w0 : 0.0f;
                w1 = ok ? w1 : 0.0f;
                acc[0][0] = f4fma(w0, a,  acc[0][0]);
                acc[1][0] = f4fma(w0, b,  acc[1][0]);
                acc[2][0] = f4fma(w0, aa, acc[2][0]);
                acc[3][0] = f4fma(w0, bb, acc[3][0]);
                acc[4][0] = f4fma(w0, ab, acc[4][0]);
                acc[0][1] = f4fma(w1, a,  acc[0][1]);
                acc[1][1] = f4fma(w1, b,  acc[1][1]);
                acc[2][1] = f4fma(w1, aa, acc[2][1]);
                acc[3][1] = f4fma(w1, bb, acc[3][1]);
                acc[4][1] = f4fma(w1, ab, acc[4][1]);
            }
        }
    }
#pragma unroll
    for (int o = 0; o < 2; ++o)
#pragma unroll
        for (int ch = 0; ch < 5; ++ch)
            sV4[ch * VPL + q * VQS + (y0 + o)] = acc[ch][o];
}

__global__ __launch_bounds__(256, 3) void ssim_fused(
        const float* __restrict__ img1, const float* __restrict__ img2,
        float* __restrict__ ws, float* __restrict__ out) {
    // sV transposed [ch][strip q][row y]: 5*612 quads * 16B = 48.96 KB
    // -> 3 blocks/CU.
    __shared__ float4 sV4[5 * VPL];

    const int tid = threadIdx.x;
    const int X0 = blockIdx.x * TX;
    const int Y0 = blockIdx.y * TY;
    const int n  = blockIdx.z;
    const float* a0 = img1 + (size_t)n * IMG * IMG;
    const float* b0 = img2 + (size_t)n * IMG * IMG;

    // Interior iff every load address is naturally in-bounds.
    const bool interior = (X0 >= 8) && (X0 - 8 + 4 * (NQ - 1) + 3 < IMG) &&
                          (Y0 >= 5) && (Y0 + TY + 4 < IMG);

    if (interior) {
        for (int it = tid; it < VITEMS; it += 256)
            vpass_item<true>(it, X0, Y0, a0, b0, sV4);
    } else {
        for (int it = tid; it < VITEMS; it += 256)
            vpass_item<false>(it, X0, Y0, a0, b0, sV4);
    }
    __syncthreads();

    // ---- horizontal pass + ssim: 8 output cols/thread, 256 items exactly.
    // 8-lane phase: y consecutive, strip fixed -> conflict-free b128.
    float sum = 0.0f;
    {
        const int y   = tid & 15;      // row 0..15
        const int grp = tid >> 4;      // 8-col group: out cols 8*grp..8*grp+7
        float res[5][8];
#pragma unroll
        for (int ch = 0; ch < 5; ++ch) {
            const float4* base = &sV4[ch * VPL + y];
            float v[24];
#pragma unroll
            for (int d = 0; d < 6; ++d) {
                const float4 t = base[(2 * grp + d) * VQS];
                v[4 * d + 0] = t.x; v[4 * d + 1] = t.y;
                v[4 * d + 2] = t.z; v[4 * d + 3] = t.w;
            }
#pragma unroll
            for (int e = 0; e < 8; ++e) {
                float s = GW[0] * v[e + 3];
#pragma unroll
                for (int k = 1; k < 11; ++k) s = fmaf(GW[k], v[e + 3 + k], s);
                res[ch][e] = s;
            }
        }
#pragma unroll
        for (int e = 0; e < 8; ++e) {
            const float mu1 = res[0][e], mu2 = res[1][e];
            const float m1s = mu1 * mu1;
            const float m2s = mu2 * mu2;
            const float m12 = mu1 * mu2;
            const float s1  = res[2][e] - m1s;
            const float s2  = res[3][e] - m2s;
            const float s12 = res[4][e] - m12;
            const float num = (2.0f * m12 + C1c) * (2.0f * s12 + C2c);
            const float den = (m1s + m2s + C1c) * (s1 + s2 + C2c);
            sum += num * __builtin_amdgcn_rcpf(den);
        }
    }

    // ---- block reduction ----
#pragma unroll
    for (int off = 32; off > 0; off >>= 1)
        sum += __shfl_down(sum, off, 64);

    __shared__ float wred[4];
    if ((tid & 63) == 0) wred[tid >> 6] = sum;
    __syncthreads();
    if (tid == 0) {
        const float s = wred[0] + wred[1] + wred[2] + wred[3];
        if (ws) {
            const int bid = blockIdx.x +
                (int)gridDim.x * (blockIdx.y + (int)gridDim.y * blockIdx.z);
            ws[bid] = s;
        } else {
            atomicAdd(out, -s * (1.0f / NPIX));
        }
    }
}

__global__ __launch_bounds__(1024) void ssim_reduce(
        const float* __restrict__ ws, float* __restrict__ out) {
    const int t = threadIdx.x;
    float s = 0.0f;
    for (int i = t; i < NBLK; i += 1024) s += ws[i];
#pragma unroll
    for (int off = 32; off > 0; off >>= 1)
        s += __shfl_down(s, off, 64);
    __shared__ float wr[16];
    if ((t & 63) == 0) wr[t >> 6] = s;
    __syncthreads();
    if (t < 64) {
        float v = (t < 16) ? wr[t] : 0.0f;
#pragma unroll
        for (int off = 8; off > 0; off >>= 1)
            v += __shfl_down(v, off, 64);
        if (t == 0) out[0] = 1.0f - v * (1.0f / NPIX);
    }
}

extern "C" void kernel_launch(void* const* d_in, const int* in_sizes, int n_in,
                              void* d_out, int out_size, void* d_ws, size_t ws_size,
                              hipStream_t stream) {
    const float* img1 = (const float*)d_in[0];
    const float* img2 = (const float*)d_in[1];
    float* out = (float*)d_out;
    const bool two_stage = (d_ws != nullptr) && (ws_size >= NBLK * sizeof(float));
    float* ws = two_stage ? (float*)d_ws : nullptr;

    if (!two_stage) ssim_init_out<<<1, 1, 0, stream>>>(out);

    dim3 grid(NBX, NBY, NIMG);   // 4 x 32 x 32 = 4096 blocks
    ssim_fused<<<grid, 256, 0, stream>>>(img1, img2, ws, out);

    if (two_stage) ssim_reduce<<<1, 1024, 0, stream>>>(ws, out);
}